// Round 1
// baseline (733.197 us; speedup 1.0000x reference)
//
#include <hip/hip_runtime.h>
#include <math.h>

#define BB 8
#define HH 128
#define WW 128
#define CC 64
#define KK 9
#define OUTC 64
#define TW 16          // pixels per block (along W)
#define CP 66          // xs channel-pad stride (keeps wtap 16B-aligned; 2-way bank alias = free)
#define COLS_P 580     // cols per-pixel stride (576 + pad, %4==0 for float4)

union __align__(16) SmemU {
    struct {
        float xs[3][TW + 2][CP];   // 3*18*66*4 = 14256 B
        float wtap[CC][32];        // 8192 B  (27 outputs used, padded to 32)
    } conv;
    float cols[TW][COLS_P];        // 16*580*4 = 37120 B
};

__global__ __launch_bounds__(256) void deform_conv_fused(
    const float* __restrict__ x,
    const float* __restrict__ offk,
    const float* __restrict__ mk,
    const float* __restrict__ filt,
    float* __restrict__ out)
{
    __shared__ SmemU sm;
    __shared__ float om[TW][28];   // 27 conv outputs per pixel (18 off + 9 mask logits)
    __shared__ float ps[TW][32];   // channel-half partial sums

    const int tid = threadIdx.x;
    const int bw = blockIdx.x % (WW / TW);
    const int h  = (blockIdx.x / (WW / TW)) % HH;
    const int b  = blockIdx.x / ((WW / TW) * HH);
    const int w0 = bw * TW;

    // ---------------- Phase 0: stage x tile [3 rows][18 cols][64 ch] ----------------
    for (int e = tid; e < 3 * (TW + 2) * (CC / 4); e += 256) {
        int r   = e / ((TW + 2) * 16);
        int rem = e % ((TW + 2) * 16);
        int col = rem / 16;
        int c4  = rem % 16;
        int y   = h + r - 1;
        int xg  = w0 + col - 1;
        float4 v = make_float4(0.f, 0.f, 0.f, 0.f);
        if (y >= 0 && y < HH && xg >= 0 && xg < WW) {
            v = *(const float4*)(x + ((size_t)(b * HH + y) * WW + xg) * CC + c4 * 4);
        }
        float* dst = &sm.conv.xs[r][col][c4 * 4];
        dst[0] = v.x; dst[1] = v.y; dst[2] = v.z; dst[3] = v.w;
    }
    __syncthreads();

    // ---------------- Phase 1: offset+mask conv (27 outputs/pixel) ----------------
    // thread = (pixel p, out-group og of 4, channel-half ch)
    const int p  = tid & 15;
    const int og = (tid >> 4) & 7;
    const int ch = tid >> 7;   // 0 or 1

    float a0 = 0.f, a1 = 0.f, a2 = 0.f, a3 = 0.f;
    for (int tap = 0; tap < 9; ++tap) {
        __syncthreads();   // protect wtap against previous-tap readers
        for (int e = tid; e < CC * 32; e += 256) {
            int c = e >> 5, o = e & 31;
            float wv = 0.f;
            if (o < 18)      wv = offk[(tap * CC + c) * 18 + o];
            else if (o < 27) wv = mk[(tap * CC + c) * 9 + (o - 18)];
            sm.conv.wtap[c][o] = wv;
        }
        __syncthreads();
        const int ty = tap / 3, tx = tap % 3;
        const float* xrow = &sm.conv.xs[ty][p + tx][0];
        const int cbase = ch * 32;
#pragma unroll 8
        for (int c = 0; c < 32; ++c) {
            float xv = xrow[cbase + c];
            float4 w4 = *(const float4*)&sm.conv.wtap[cbase + c][og * 4];
            a0 = fmaf(xv, w4.x, a0);
            a1 = fmaf(xv, w4.y, a1);
            a2 = fmaf(xv, w4.z, a2);
            a3 = fmaf(xv, w4.w, a3);
        }
    }
    __syncthreads();           // conv reads of xs/wtap complete
    if (ch == 1) {
        ps[p][og * 4 + 0] = a0; ps[p][og * 4 + 1] = a1;
        ps[p][og * 4 + 2] = a2; ps[p][og * 4 + 3] = a3;
    }
    __syncthreads();
    if (ch == 0) {
        a0 += ps[p][og * 4 + 0]; a1 += ps[p][og * 4 + 1];
        a2 += ps[p][og * 4 + 2]; a3 += ps[p][og * 4 + 3];
        int o0 = og * 4;
        if (o0 + 0 < 27) om[p][o0 + 0] = a0;
        if (o0 + 1 < 27) om[p][o0 + 1] = a1;
        if (o0 + 2 < 27) om[p][o0 + 2] = a2;
        if (o0 + 3 < 27) om[p][o0 + 3] = a3;
    }
    __syncthreads();

    // ---------------- Phase 2: bilinear gather -> cols[p][c*9+k] (overwrites conv LDS) --
    for (int s = tid; s < 2 * TW * KK; s += 256) {   // 288 slots = (pixel,tap) x ch-half
        int pair = s >> 1, chh = s & 1;
        int pp = pair / KK, kk = pair % KK;
        float dy = om[pp][2 * kk];
        float dx = om[pp][2 * kk + 1];
        float mlog = om[pp][18 + kk];
        float m = 1.f / (1.f + expf(-mlog));
        int ky = kk / 3, kx = kk % 3;
        float py = (float)(h + ky - 1) + dy;
        float px = (float)(w0 + pp + kx - 1) + dx;
        float y0 = floorf(py), x0 = floorf(px);
        float ly = py - y0, lx = px - x0;
        float y1 = y0 + 1.f, x1 = x0 + 1.f;
        bool vy0 = (y0 >= 0.f) && (y0 <= (float)(HH - 1));
        bool vy1 = (y1 >= 0.f) && (y1 <= (float)(HH - 1));
        bool vx0 = (x0 >= 0.f) && (x0 <= (float)(WW - 1));
        bool vx1 = (x1 >= 0.f) && (x1 <= (float)(WW - 1));
        float w00 = (vy0 && vx0) ? (1.f - ly) * (1.f - lx) * m : 0.f;
        float w01 = (vy0 && vx1) ? (1.f - ly) * lx * m : 0.f;
        float w10 = (vy1 && vx0) ? ly * (1.f - lx) * m : 0.f;
        float w11 = (vy1 && vx1) ? ly * lx * m : 0.f;
        int iy0 = (int)fminf(fmaxf(y0, 0.f), (float)(HH - 1));
        int iy1 = (int)fminf(fmaxf(y1, 0.f), (float)(HH - 1));
        int ix0 = (int)fminf(fmaxf(x0, 0.f), (float)(WW - 1));
        int ix1 = (int)fminf(fmaxf(x1, 0.f), (float)(WW - 1));
        const float* b00 = x + ((size_t)(b * HH + iy0) * WW + ix0) * CC + chh * 32;
        const float* b01 = x + ((size_t)(b * HH + iy0) * WW + ix1) * CC + chh * 32;
        const float* b10 = x + ((size_t)(b * HH + iy1) * WW + ix0) * CC + chh * 32;
        const float* b11 = x + ((size_t)(b * HH + iy1) * WW + ix1) * CC + chh * 32;
        float* cdst = &sm.cols[pp][kk];
#pragma unroll
        for (int c4 = 0; c4 < 8; ++c4) {
            float4 v00 = *(const float4*)(b00 + c4 * 4);
            float4 v01 = *(const float4*)(b01 + c4 * 4);
            float4 v10 = *(const float4*)(b10 + c4 * 4);
            float4 v11 = *(const float4*)(b11 + c4 * 4);
            float4 v;
            v.x = w00 * v00.x + w01 * v01.x + w10 * v10.x + w11 * v11.x;
            v.y = w00 * v00.y + w01 * v01.y + w10 * v10.y + w11 * v11.y;
            v.z = w00 * v00.z + w01 * v01.z + w10 * v10.z + w11 * v11.z;
            v.w = w00 * v00.w + w01 * v01.w + w10 * v10.w + w11 * v11.w;
            int cb = chh * 32 + c4 * 4;
            cdst[(cb + 0) * KK] = v.x;
            cdst[(cb + 1) * KK] = v.y;
            cdst[(cb + 2) * KK] = v.z;
            cdst[(cb + 3) * KK] = v.w;
        }
    }
    __syncthreads();

    // ---------------- Phase 3: per-pixel GEMM out[p][o] = cols[p][:] . filt[o][:] ------
    const int eog = tid >> 4;   // 0..15 -> 4 outputs each
    float o0 = 0.f, o1 = 0.f, o2 = 0.f, o3 = 0.f;
    const float* fbase = filt + (size_t)eog * 4 * 576;
    const float* crow = &sm.cols[p][0];
#pragma unroll 4
    for (int kc = 0; kc < 576; kc += 4) {
        float4 cv = *(const float4*)(crow + kc);
        float4 f0 = *(const float4*)(fbase + 0 * 576 + kc);
        float4 f1 = *(const float4*)(fbase + 1 * 576 + kc);
        float4 f2 = *(const float4*)(fbase + 2 * 576 + kc);
        float4 f3 = *(const float4*)(fbase + 3 * 576 + kc);
        o0 = fmaf(cv.x, f0.x, o0); o0 = fmaf(cv.y, f0.y, o0);
        o0 = fmaf(cv.z, f0.z, o0); o0 = fmaf(cv.w, f0.w, o0);
        o1 = fmaf(cv.x, f1.x, o1); o1 = fmaf(cv.y, f1.y, o1);
        o1 = fmaf(cv.z, f1.z, o1); o1 = fmaf(cv.w, f1.w, o1);
        o2 = fmaf(cv.x, f2.x, o2); o2 = fmaf(cv.y, f2.y, o2);
        o2 = fmaf(cv.z, f2.z, o2); o2 = fmaf(cv.w, f2.w, o2);
        o3 = fmaf(cv.x, f3.x, o3); o3 = fmaf(cv.y, f3.y, o3);
        o3 = fmaf(cv.z, f3.z, o3); o3 = fmaf(cv.w, f3.w, o3);
    }
    size_t oidx = ((size_t)(b * HH + h) * WW + (w0 + p)) * OUTC + eog * 4;
    *(float4*)(out + oidx) = make_float4(o0, o1, o2, o3);
}

extern "C" void kernel_launch(void* const* d_in, const int* in_sizes, int n_in,
                              void* d_out, int out_size, void* d_ws, size_t ws_size,
                              hipStream_t stream) {
    const float* x    = (const float*)d_in[0];
    const float* offk = (const float*)d_in[1];
    const float* mk   = (const float*)d_in[2];
    const float* filt = (const float*)d_in[3];
    float* out = (float*)d_out;
    const int blocks = BB * HH * (WW / TW);   // 8192
    deform_conv_fused<<<blocks, 256, 0, stream>>>(x, offk, mk, filt, out);
}

// Round 2
// 324.244 us; speedup vs baseline: 2.2612x; 2.2612x over previous
//
#include <hip/hip_runtime.h>
#include <math.h>

#define BB 8
#define HH 128
#define WW 128
#define CC 64
#define KK 9
#define OUTC 64
#define TW 16
#define KTOT 576           // K = 9 taps * 64 ch, kappa = k*64 + c
#define NKS 18             // K-steps of 32

typedef __attribute__((ext_vector_type(8))) short short8v;
typedef __attribute__((ext_vector_type(4))) float float4v;

static __device__ __forceinline__ unsigned short f2bf(float f) {
    unsigned int u = __float_as_uint(f);
    return (unsigned short)((u + 0x7FFFu + ((u >> 16) & 1u)) >> 16);
}
static __device__ __forceinline__ float bf2f(unsigned short h) {
    return __uint_as_float(((unsigned int)h) << 16);
}

// MFMA-fragment-order LDS offset (ushort units) for (pixel p, kappa).
// Lane l of K-step ks reads 16B at byte (ks*1024 + l*16): conflict-free.
static __device__ __forceinline__ int frag_off(int p, int kappa) {
    int chunk = kappa >> 3;
    return ((chunk >> 2) << 9) + ((chunk & 3) << 7) + (p << 3) + (kappa & 7);
}

// ---- prep: fp32 -> bf16 weight panels in ws, reordered to [o][k*64+c] ----
__global__ __launch_bounds__(256) void prep_weights(
    const float* __restrict__ offk, const float* __restrict__ mk,
    const float* __restrict__ filt,
    unsigned short* __restrict__ fb,   // [64][576]
    unsigned short* __restrict__ wc)   // [32][576]
{
    int i = blockIdx.x * 256 + threadIdx.x;
    if (i < OUTC * KTOT) {
        int o = i / KTOT, kp = i % KTOT;
        int k = kp >> 6, c = kp & 63;
        fb[i] = f2bf(filt[o * 576 + c * 9 + k]);
    }
    if (i < 32 * KTOT) {
        int o = i / KTOT, kp = i % KTOT;
        int k = kp >> 6, c = kp & 63;
        float v = 0.f;
        if (o < 18)      v = offk[(k * 64 + c) * 18 + o];
        else if (o < 27) v = mk[(k * 64 + c) * 9 + (o - 18)];
        wc[i] = f2bf(v);
    }
}

__global__ __launch_bounds__(256) void deform_conv_fused(
    const float* __restrict__ x,
    const unsigned short* __restrict__ fb,
    const unsigned short* __restrict__ wc,
    float* __restrict__ out)
{
    __shared__ __align__(16) unsigned short ims_hi[TW * KTOT]; // 18432B; cols overlays
    __shared__ __align__(16) unsigned short ims_lo[TW * KTOT]; // 18432B
    __shared__ float ps2[4][TW][16];                            // 4096B conv partials
    __shared__ float om[TW][28];                                // raw conv outputs

    const int tid  = threadIdx.x;
    const int lane = tid & 63;
    const int wave = tid >> 6;
    const int bw = blockIdx.x % (WW / TW);
    const int h  = (blockIdx.x / (WW / TW)) % HH;
    const int b  = blockIdx.x / ((WW / TW) * HH);
    const int w0 = bw * TW;

    // -------- Phase A: static im2col, bf16 hi + residual lo, fragment order ------
    for (int e = tid; e < KK * 16 * TW; e += 256) {     // 2304 tasks, p innermost
        int p  = e & 15;
        int kc = e >> 4;            // 0..143
        int k  = kc >> 4;           // tap
        int c4 = kc & 15;           // channel quad
        int y  = h + k / 3 - 1;
        int xg = w0 + p + (k % 3) - 1;
        float4 v = make_float4(0.f, 0.f, 0.f, 0.f);
        if (y >= 0 && y < HH && xg >= 0 && xg < WW)
            v = *(const float4*)(x + ((size_t)(b * HH + y) * WW + xg) * CC + c4 * 4);
        float vv[4] = {v.x, v.y, v.z, v.w};
        unsigned short hs[4], ls[4];
#pragma unroll
        for (int j = 0; j < 4; ++j) {
            hs[j] = f2bf(vv[j]);
            ls[j] = f2bf(vv[j] - bf2f(hs[j]));
        }
        int off = frag_off(p, k * 64 + c4 * 4);    // 8B-aligned
        *(uint2*)(ims_hi + off) = make_uint2((unsigned)hs[0] | ((unsigned)hs[1] << 16),
                                             (unsigned)hs[2] | ((unsigned)hs[3] << 16));
        *(uint2*)(ims_lo + off) = make_uint2((unsigned)ls[0] | ((unsigned)ls[1] << 16),
                                             (unsigned)ls[2] | ((unsigned)ls[3] << 16));
    }
    __syncthreads();

    // -------- Phase B: offset+mask conv via MFMA (wave = (part, nhalf)) ----------
    {
        const int nh = wave & 1, part = wave >> 1;
        const unsigned short* A = part ? ims_lo : ims_hi;
        const int pl = lane & 15;
        const unsigned short* Bp = wc + (nh * 16 + pl) * KTOT;
        float4v acc = {0.f, 0.f, 0.f, 0.f};
#pragma unroll
        for (int ks = 0; ks < NKS; ++ks) {
            short8v a  = *(const short8v*)(A + ks * 512 + lane * 8);
            short8v bf = *(const short8v*)(Bp + ks * 32 + (lane >> 4) * 8);
            acc = __builtin_amdgcn_mfma_f32_16x16x32_bf16(a, bf, acc, 0, 0, 0);
        }
        const int lg = lane >> 4;
#pragma unroll
        for (int r = 0; r < 4; ++r)
            ps2[wave][lg * 4 + r][pl] = acc[r];
    }
    __syncthreads();
    for (int idx = tid; idx < TW * 27; idx += 256) {    // hi+lo partial reduce
        int p = idx / 27, o = idx % 27;
        int nh = o >> 4, ol = o & 15;
        om[p][o] = ps2[nh][p][ol] + ps2[nh + 2][p][ol];
    }
    __syncthreads();

    // -------- Phase C: bilinear gather -> cols (bf16, fragment order) ------------
    unsigned short* cols = ims_hi;   // overlay (conv reads finished)
    for (int s = tid; s < 2 * TW * KK; s += 256) {      // (pixel,tap) x ch-half
        int pair = s >> 1, chh = s & 1;
        int pp = pair / KK, kk = pair % KK;
        float dy = om[pp][2 * kk];
        float dx = om[pp][2 * kk + 1];
        float m  = 1.f / (1.f + __expf(-om[pp][18 + kk]));
        int ky = kk / 3, kx = kk % 3;
        float py = (float)(h + ky - 1) + dy;
        float px = (float)(w0 + pp + kx - 1) + dx;
        float y0 = floorf(py), x0 = floorf(px);
        float ly = py - y0, lx = px - x0;
        float y1 = y0 + 1.f, x1 = x0 + 1.f;
        bool vy0 = (y0 >= 0.f) && (y0 <= (float)(HH - 1));
        bool vy1 = (y1 >= 0.f) && (y1 <= (float)(HH - 1));
        bool vx0 = (x0 >= 0.f) && (x0 <= (float)(WW - 1));
        bool vx1 = (x1 >= 0.f) && (x1 <= (float)(WW - 1));
        float w00 = (vy0 && vx0) ? (1.f - ly) * (1.f - lx) * m : 0.f;
        float w01 = (vy0 && vx1) ? (1.f - ly) * lx * m : 0.f;
        float w10 = (vy1 && vx0) ? ly * (1.f - lx) * m : 0.f;
        float w11 = (vy1 && vx1) ? ly * lx * m : 0.f;
        int iy0 = (int)fminf(fmaxf(y0, 0.f), (float)(HH - 1));
        int iy1 = (int)fminf(fmaxf(y1, 0.f), (float)(HH - 1));
        int ix0 = (int)fminf(fmaxf(x0, 0.f), (float)(WW - 1));
        int ix1 = (int)fminf(fmaxf(x1, 0.f), (float)(WW - 1));
        const float* b00 = x + ((size_t)(b * HH + iy0) * WW + ix0) * CC + chh * 32;
        const float* b01 = x + ((size_t)(b * HH + iy0) * WW + ix1) * CC + chh * 32;
        const float* b10 = x + ((size_t)(b * HH + iy1) * WW + ix0) * CC + chh * 32;
        const float* b11 = x + ((size_t)(b * HH + iy1) * WW + ix1) * CC + chh * 32;
#pragma unroll
        for (int c4 = 0; c4 < 8; ++c4) {
            float4 v00 = *(const float4*)(b00 + c4 * 4);
            float4 v01 = *(const float4*)(b01 + c4 * 4);
            float4 v10 = *(const float4*)(b10 + c4 * 4);
            float4 v11 = *(const float4*)(b11 + c4 * 4);
            float r0 = w00 * v00.x + w01 * v01.x + w10 * v10.x + w11 * v11.x;
            float r1 = w00 * v00.y + w01 * v01.y + w10 * v10.y + w11 * v11.y;
            float r2 = w00 * v00.z + w01 * v01.z + w10 * v10.z + w11 * v11.z;
            float r3 = w00 * v00.w + w01 * v01.w + w10 * v10.w + w11 * v11.w;
            unsigned short q0 = f2bf(r0), q1 = f2bf(r1), q2 = f2bf(r2), q3 = f2bf(r3);
            int off = frag_off(pp, kk * 64 + chh * 32 + c4 * 4);
            *(uint2*)(cols + off) = make_uint2((unsigned)q0 | ((unsigned)q1 << 16),
                                               (unsigned)q2 | ((unsigned)q3 << 16));
        }
    }
    __syncthreads();

    // -------- Phase D: main einsum via MFMA (wave owns 16 outputs) ---------------
    {
        const int pl = lane & 15;
        const unsigned short* Bp = fb + (wave * 16 + pl) * KTOT;
        float4v acc = {0.f, 0.f, 0.f, 0.f};
#pragma unroll
        for (int ks = 0; ks < NKS; ++ks) {
            short8v a  = *(const short8v*)(cols + ks * 512 + lane * 8);
            short8v bf = *(const short8v*)(Bp + ks * 32 + (lane >> 4) * 8);
            acc = __builtin_amdgcn_mfma_f32_16x16x32_bf16(a, bf, acc, 0, 0, 0);
        }
        const int o  = wave * 16 + pl;
        const int lg = lane >> 4;
#pragma unroll
        for (int r = 0; r < 4; ++r) {
            int p = lg * 4 + r;
            out[((size_t)(b * HH + h) * WW + (w0 + p)) * OUTC + o] = acc[r];
        }
    }
}

extern "C" void kernel_launch(void* const* d_in, const int* in_sizes, int n_in,
                              void* d_out, int out_size, void* d_ws, size_t ws_size,
                              hipStream_t stream) {
    const float* x    = (const float*)d_in[0];
    const float* offk = (const float*)d_in[1];
    const float* mk   = (const float*)d_in[2];
    const float* filt = (const float*)d_in[3];
    float* out = (float*)d_out;
    // ws: fb (64*576 bf16) + wc (32*576 bf16) = 110592 B
    unsigned short* fb = (unsigned short*)d_ws;
    unsigned short* wc = fb + OUTC * KTOT;
    prep_weights<<<144, 256, 0, stream>>>(offk, mk, filt, fb, wc);
    deform_conv_fused<<<BB * HH * (WW / TW), 256, 0, stream>>>(x, fb, wc, out);
}

// Round 3
// 227.786 us; speedup vs baseline: 3.2188x; 1.4235x over previous
//
#include <hip/hip_runtime.h>
#include <math.h>

#define BB 8
#define HH 128
#define WW 128
#define CC 64
#define KK 9
#define OUTC 64
#define TW 16
#define KTOT 576          // kappa = k*64 + c
#define NELEM (BB*HH*WW*CC)

typedef __attribute__((ext_vector_type(8))) short short8v;
typedef __attribute__((ext_vector_type(4))) float float4v;

static __device__ __forceinline__ unsigned short f2bf(float f) {
    unsigned int u = __float_as_uint(f);
    return (unsigned short)((u + 0x7FFFu + ((u >> 16) & 1u)) >> 16);
}
static __device__ __forceinline__ float bf2f(unsigned short h) {
    return __uint_as_float(((unsigned int)h) << 16);
}
static __device__ __forceinline__ float bf2f_lo(unsigned int w) {
    return __uint_as_float(w << 16);
}
static __device__ __forceinline__ float bf2f_hi(unsigned int w) {
    return __uint_as_float(w & 0xFFFF0000u);
}

// Swizzled MFMA-fragment LDS offset (ushort units) for (pixel p, kappa).
// chunk = kappa>>3; pixel field XOR'd with chunk&7 so same-pixel writes
// across chunks spread over all 32 banks. MFMA read: lane l, K-step ks
// reads shorts at ks*512 + lg*128 + ((pl ^ ((ks&1)?lg+4:lg))<<3).
static __device__ __forceinline__ int frag_addr(int p, int kappa) {
    int chunk = kappa >> 3;
    return ((chunk >> 2) << 9) + ((chunk & 3) << 7) + ((p ^ (chunk & 7)) << 3) + (kappa & 7);
}

// ---- prep: weights -> bf16 panels; x -> bf16 copy (for gather) ----
__global__ __launch_bounds__(256) void prep_all(
    const float* __restrict__ x, const float* __restrict__ offk,
    const float* __restrict__ mk, const float* __restrict__ filt,
    unsigned short* __restrict__ fb,   // [64][576]
    unsigned short* __restrict__ wc,   // [32][576]
    unsigned short* __restrict__ xb,   // bf16 copy of x
    int do_x)
{
    int bid = blockIdx.x, tid = threadIdx.x;
    if (bid < 144) {
        int i = bid * 256 + tid;
        {   // fb: all 36864 covered
            int o = i / KTOT, kp = i % KTOT;
            int k = kp >> 6, c = kp & 63;
            fb[i] = f2bf(filt[(o * CC + c) * KK + k]);
        }
        if (i < 32 * KTOT) {
            int o = i / KTOT, kp = i % KTOT;
            int k = kp >> 6, c = kp & 63;
            float v = 0.f;
            if (o < 18)      v = offk[(k * CC + c) * 18 + o];
            else if (o < 27) v = mk[(k * CC + c) * 9 + (o - 18)];
            wc[i] = f2bf(v);
        }
        return;
    }
    if (!do_x) return;
    int i = (bid - 144) * 256 + tid;          // 8 elems per thread, 4096 blocks exact
    float4 a = *(const float4*)(x + (size_t)i * 8);
    float4 c = *(const float4*)(x + (size_t)i * 8 + 4);
    uint4 q;
    q.x = (unsigned)f2bf(a.x) | ((unsigned)f2bf(a.y) << 16);
    q.y = (unsigned)f2bf(a.z) | ((unsigned)f2bf(a.w) << 16);
    q.z = (unsigned)f2bf(c.x) | ((unsigned)f2bf(c.y) << 16);
    q.w = (unsigned)f2bf(c.z) | ((unsigned)f2bf(c.w) << 16);
    *(uint4*)(xb + (size_t)i * 8) = q;
}

__global__ __launch_bounds__(256, 6) void deform_conv_fused(
    const float* __restrict__ x,
    const unsigned short* __restrict__ xb,   // bf16 x or nullptr
    const unsigned short* __restrict__ fb,
    const unsigned short* __restrict__ wc,
    float* __restrict__ out)
{
    __shared__ __align__(16) unsigned short ims[TW * KTOT];   // 18432 B (cols overlay)
    __shared__ __align__(16) union UU {
        float ps2[4][TW][18];                                  // 4608 B conv partials
        struct { int c[144][4]; float w[144][4]; } gs;         // 4608 B gather setup
    } u;
    __shared__ float om[TW][28];                               // 1792 B conv outputs

    const int tid  = threadIdx.x;
    const int lane = tid & 63;
    const int wave = tid >> 6;
    const int pl = lane & 15;
    const int lg = lane >> 4;
    const int off_e = lg * 128 + ((pl ^ lg) << 3);
    const int off_o = lg * 128 + ((pl ^ (lg + 4)) << 3);

    // XCD swizzle: 8192 blocks, %8==0 -> each XCD owns one full image b.
    const int swz = (blockIdx.x & 7) * 1024 + (blockIdx.x >> 3);
    const int bw = swz & 7;
    const int h  = (swz >> 3) & 127;
    const int b  = swz >> 10;
    const int w0 = bw * TW;

    // -------- Phases A/B x2: two-pass (hi, lo) im2col + conv MFMA ----------------
    const int nh = wave & 1, kh = wave >> 1;   // wave = (K-half, N-half)
    float4v acc = {0.f, 0.f, 0.f, 0.f};
    const unsigned short* Bc = wc + (nh * 16 + pl) * KTOT;
#pragma unroll
    for (int pass = 0; pass < 2; ++pass) {
        for (int e = tid; e < KK * 16 * TW; e += 256) {   // 9 iters
            int p = e & 15, kc = e >> 4, k = kc >> 4, c4 = kc & 15;
            int y = h + (k / 3) - 1, xg = w0 + p + (k % 3) - 1;
            float4 v = make_float4(0.f, 0.f, 0.f, 0.f);
            if ((unsigned)y < HH && (unsigned)xg < WW)
                v = *(const float4*)(x + ((size_t)((b * HH + y) * WW + xg)) * CC + c4 * 4);
            float vv[4] = {v.x, v.y, v.z, v.w};
            unsigned short q[4];
#pragma unroll
            for (int j = 0; j < 4; ++j) {
                unsigned short hi0 = f2bf(vv[j]);
                q[j] = (pass == 0) ? hi0 : f2bf(vv[j] - bf2f(hi0));
            }
            *(uint2*)(ims + frag_addr(p, k * 64 + c4 * 4)) =
                make_uint2((unsigned)q[0] | ((unsigned)q[1] << 16),
                           (unsigned)q[2] | ((unsigned)q[3] << 16));
        }
        __syncthreads();
#pragma unroll
        for (int ks9 = 0; ks9 < 9; ++ks9) {
            int ks = kh * 9 + ks9;
            short8v a  = *(const short8v*)(ims + ks * 512 + ((ks & 1) ? off_o : off_e));
            short8v bv = *(const short8v*)(Bc + ks * 32 + lg * 8);
            acc = __builtin_amdgcn_mfma_f32_16x16x32_bf16(a, bv, acc, 0, 0, 0);
        }
        __syncthreads();
    }
#pragma unroll
    for (int r = 0; r < 4; ++r)
        u.ps2[wave][lg * 4 + r][pl] = acc[r];
    __syncthreads();

    // -------- reduce partials -> om[pixel][27] ------------------------------------
    for (int idx = tid; idx < TW * 27; idx += 256) {
        int p = idx / 27, o = idx % 27;
        int nhh = o >> 4, ol = o & 15;
        om[p][o] = u.ps2[nhh][p][ol] + u.ps2[2 + nhh][p][ol];
    }
    __syncthreads();

    // -------- gather setup: per (pixel,tap) corner bases + folded weights ---------
    if (tid < 144) {
        int p = tid / 9, k = tid - (tid / 9) * 9;
        float dy = om[p][2 * k], dx = om[p][2 * k + 1];
        float m  = 1.f / (1.f + __expf(-om[p][18 + k]));
        float py = (float)(h + (k / 3) - 1) + dy;
        float px = (float)(w0 + p + (k % 3) - 1) + dx;
        float y0 = floorf(py), x0 = floorf(px);
        float ly = py - y0, lx = px - x0;
        bool vy0 = (y0 >= 0.f)  && (y0 <= 127.f);
        bool vy1 = (y0 >= -1.f) && (y0 <= 126.f);
        bool vx0 = (x0 >= 0.f)  && (x0 <= 127.f);
        bool vx1 = (x0 >= -1.f) && (x0 <= 126.f);
        float wy0 = 1.f - ly, wx0 = 1.f - lx;
        int iy0 = (int)fminf(fmaxf(y0, 0.f), 127.f);
        int iy1 = (int)fminf(fmaxf(y0 + 1.f, 0.f), 127.f);
        int ix0 = (int)fminf(fmaxf(x0, 0.f), 127.f);
        int ix1 = (int)fminf(fmaxf(x0 + 1.f, 0.f), 127.f);
        int base = b * (HH * WW * CC);
        u.gs.c[tid][0] = base + (iy0 * WW + ix0) * CC;
        u.gs.c[tid][1] = base + (iy0 * WW + ix1) * CC;
        u.gs.c[tid][2] = base + (iy1 * WW + ix0) * CC;
        u.gs.c[tid][3] = base + (iy1 * WW + ix1) * CC;
        u.gs.w[tid][0] = (vy0 && vx0) ? wy0 * wx0 * m : 0.f;
        u.gs.w[tid][1] = (vy0 && vx1) ? wy0 * lx  * m : 0.f;
        u.gs.w[tid][2] = (vy1 && vx0) ? ly  * wx0 * m : 0.f;
        u.gs.w[tid][3] = (vy1 && vx1) ? ly  * lx  * m : 0.f;
    }
    __syncthreads();

    // -------- gather: 1152 tasks (pair, c8), 8 ch each; lanes coalesce per corner -
    if (xb) {
        for (int t = tid; t < 1152; t += 256) {
            int pair = t >> 3, c8 = t & 7;
            int p = pair / 9, k = pair - (pair / 9) * 9;
            int4   cc = *(const int4*)(&u.gs.c[pair][0]);
            float4 wv = *(const float4*)(&u.gs.w[pair][0]);
            int co = c8 * 8;
            uint4 u00 = *(const uint4*)(xb + cc.x + co);
            uint4 u01 = *(const uint4*)(xb + cc.y + co);
            uint4 u10 = *(const uint4*)(xb + cc.z + co);
            uint4 u11 = *(const uint4*)(xb + cc.w + co);
            const unsigned* a00 = (const unsigned*)&u00;
            const unsigned* a01 = (const unsigned*)&u01;
            const unsigned* a10 = (const unsigned*)&u10;
            const unsigned* a11 = (const unsigned*)&u11;
            unsigned qq[4];
#pragma unroll
            for (int jj = 0; jj < 4; ++jj) {
                float rl = wv.x * bf2f_lo(a00[jj]) + wv.y * bf2f_lo(a01[jj])
                         + wv.z * bf2f_lo(a10[jj]) + wv.w * bf2f_lo(a11[jj]);
                float rh = wv.x * bf2f_hi(a00[jj]) + wv.y * bf2f_hi(a01[jj])
                         + wv.z * bf2f_hi(a10[jj]) + wv.w * bf2f_hi(a11[jj]);
                qq[jj] = (unsigned)f2bf(rl) | ((unsigned)f2bf(rh) << 16);
            }
            *(uint4*)(ims + frag_addr(p, k * 64 + co)) = make_uint4(qq[0], qq[1], qq[2], qq[3]);
        }
    } else {   // fp32 fallback when ws too small for xb
        for (int t = tid; t < 1152; t += 256) {
            int pair = t >> 3, c8 = t & 7;
            int p = pair / 9, k = pair - (pair / 9) * 9;
            int4   cc = *(const int4*)(&u.gs.c[pair][0]);
            float4 wv = *(const float4*)(&u.gs.w[pair][0]);
            int co = c8 * 8;
            float r[8];
#pragma unroll
            for (int half = 0; half < 2; ++half) {
                float4 v00 = *(const float4*)(x + cc.x + co + half * 4);
                float4 v01 = *(const float4*)(x + cc.y + co + half * 4);
                float4 v10 = *(const float4*)(x + cc.z + co + half * 4);
                float4 v11 = *(const float4*)(x + cc.w + co + half * 4);
                r[half * 4 + 0] = wv.x * v00.x + wv.y * v01.x + wv.z * v10.x + wv.w * v11.x;
                r[half * 4 + 1] = wv.x * v00.y + wv.y * v01.y + wv.z * v10.y + wv.w * v11.y;
                r[half * 4 + 2] = wv.x * v00.z + wv.y * v01.z + wv.z * v10.z + wv.w * v11.z;
                r[half * 4 + 3] = wv.x * v00.w + wv.y * v01.w + wv.z * v10.w + wv.w * v11.w;
            }
            unsigned qq[4];
#pragma unroll
            for (int jj = 0; jj < 4; ++jj)
                qq[jj] = (unsigned)f2bf(r[2 * jj]) | ((unsigned)f2bf(r[2 * jj + 1]) << 16);
            *(uint4*)(ims + frag_addr(p, k * 64 + co)) = make_uint4(qq[0], qq[1], qq[2], qq[3]);
        }
    }
    __syncthreads();

    // -------- main einsum: wave owns 16 outputs ------------------------------------
    {
        const unsigned short* Bp = fb + (wave * 16 + pl) * KTOT;
        float4v acc2 = {0.f, 0.f, 0.f, 0.f};
#pragma unroll
        for (int ks = 0; ks < 18; ++ks) {
            short8v a  = *(const short8v*)(ims + ks * 512 + ((ks & 1) ? off_o : off_e));
            short8v bv = *(const short8v*)(Bp + ks * 32 + lg * 8);
            acc2 = __builtin_amdgcn_mfma_f32_16x16x32_bf16(a, bv, acc2, 0, 0, 0);
        }
        const int o = wave * 16 + pl;
        const size_t rowbase = (size_t)(b * HH + h) * WW + w0;
#pragma unroll
        for (int r = 0; r < 4; ++r) {
            int p = lg * 4 + r;
            out[(rowbase + p) * OUTC + o] = acc2[r];
        }
    }
}

extern "C" void kernel_launch(void* const* d_in, const int* in_sizes, int n_in,
                              void* d_out, int out_size, void* d_ws, size_t ws_size,
                              hipStream_t stream) {
    const float* x    = (const float*)d_in[0];
    const float* offk = (const float*)d_in[1];
    const float* mk   = (const float*)d_in[2];
    const float* filt = (const float*)d_in[3];
    float* out = (float*)d_out;
    unsigned short* fb = (unsigned short*)d_ws;                 // 73728 B
    unsigned short* wc = fb + OUTC * KTOT;                      // 36864 B
    unsigned short* xb = wc + 32 * KTOT;                        // 16.8 MB
    size_t need = (size_t)(OUTC + 32) * KTOT * 2 + (size_t)NELEM * 2;
    int do_x = (ws_size >= need) ? 1 : 0;
    prep_all<<<144 + (do_x ? 4096 : 0), 256, 0, stream>>>(x, offk, mk, filt, fb, wc, xb, do_x);
    deform_conv_fused<<<BB * HH * (WW / TW), 256, 0, stream>>>(
        x, do_x ? xb : (const unsigned short*)nullptr, fb, wc, out);
}

// Round 4
// 194.636 us; speedup vs baseline: 3.7670x; 1.1703x over previous
//
#include <hip/hip_runtime.h>
#include <math.h>

#define BB 8
#define HH 128
#define WW 128
#define CC 64
#define KK 9
#define OUTC 64
#define TW 16
#define KTOT 576          // kappa = k*64 + c
#define NELEM (BB*HH*WW*CC)

typedef __attribute__((ext_vector_type(8))) short short8v;
typedef __attribute__((ext_vector_type(4))) float float4v;

static __device__ __forceinline__ unsigned short f2bf(float f) {
    unsigned int u = __float_as_uint(f);
    return (unsigned short)((u + 0x7FFFu + ((u >> 16) & 1u)) >> 16);
}
static __device__ __forceinline__ float bf2f(unsigned short h) {
    return __uint_as_float(((unsigned int)h) << 16);
}
static __device__ __forceinline__ float bf2f_lo(unsigned int w) {
    return __uint_as_float(w << 16);
}
static __device__ __forceinline__ float bf2f_hi(unsigned int w) {
    return __uint_as_float(w & 0xFFFF0000u);
}

// Swizzled MFMA-fragment LDS offset (ushort units) for (pixel p, kappa).
// chunk = kappa>>3; pixel field XOR'd with chunk&7 -> same-pixel writes
// across chunks spread over all 32 banks. MFMA read: lane l, K-step ks
// reads shorts at ks*512 + lg*128 + ((pl ^ (lg + 4*(ks&1)))<<3).
static __device__ __forceinline__ int frag_addr(int p, int kappa) {
    int chunk = kappa >> 3;
    return ((chunk >> 2) << 9) + ((chunk & 3) << 7) + ((p ^ (chunk & 7)) << 3) + (kappa & 7);
}

// ---- prep: weights -> bf16 panels; x -> bf16 hi + bf16 residual lo ----
__global__ __launch_bounds__(256) void prep_all(
    const float* __restrict__ x, const float* __restrict__ offk,
    const float* __restrict__ mk, const float* __restrict__ filt,
    unsigned short* __restrict__ fb,   // [64][576]
    unsigned short* __restrict__ wc,   // [32][576]
    unsigned short* __restrict__ xh,   // bf16 hi of x
    unsigned short* __restrict__ xl,   // bf16 residual of x
    int do_x)
{
    int bid = blockIdx.x, tid = threadIdx.x;
    if (bid < 144) {
        int i = bid * 256 + tid;
        {   // fb: all 36864 covered
            int o = i / KTOT, kp = i % KTOT;
            int k = kp >> 6, c = kp & 63;
            fb[i] = f2bf(filt[(o * CC + c) * KK + k]);
        }
        if (i < 32 * KTOT) {
            int o = i / KTOT, kp = i % KTOT;
            int k = kp >> 6, c = kp & 63;
            float v = 0.f;
            if (o < 18)      v = offk[(k * CC + c) * 18 + o];
            else if (o < 27) v = mk[(k * CC + c) * 9 + (o - 18)];
            wc[i] = f2bf(v);
        }
        return;
    }
    if (!do_x) return;
    int i = (bid - 144) * 256 + tid;          // 8 elems/thread, 4096 blocks exact
    const float* src = x + (size_t)i * 8;
    float4 a = *(const float4*)(src);
    float4 c = *(const float4*)(src + 4);
    float v[8] = {a.x, a.y, a.z, a.w, c.x, c.y, c.z, c.w};
    unsigned hq[4], lq[4];
#pragma unroll
    for (int j = 0; j < 4; ++j) {
        unsigned short h0 = f2bf(v[2 * j]),     h1 = f2bf(v[2 * j + 1]);
        unsigned short l0 = f2bf(v[2 * j] - bf2f(h0));
        unsigned short l1 = f2bf(v[2 * j + 1] - bf2f(h1));
        hq[j] = (unsigned)h0 | ((unsigned)h1 << 16);
        lq[j] = (unsigned)l0 | ((unsigned)l1 << 16);
    }
    *(uint4*)(xh + (size_t)i * 8) = make_uint4(hq[0], hq[1], hq[2], hq[3]);
    *(uint4*)(xl + (size_t)i * 8) = make_uint4(lq[0], lq[1], lq[2], lq[3]);
}

template<int HASB>
__global__ __launch_bounds__(256, 6) void deform_conv_fused(
    const float* __restrict__ x,
    const unsigned short* __restrict__ xh,
    const unsigned short* __restrict__ xl,
    const unsigned short* __restrict__ fb,
    const unsigned short* __restrict__ wc,
    float* __restrict__ out)
{
    __shared__ __align__(16) unsigned short ims[TW * KTOT];   // 18432 B (cols)
    __shared__ __align__(16) union UU {
        float ps2[4][TW][18];                                  // 4608 B conv partials
        struct { int c[144][4]; float w[144][4]; } gs;         // 4608 B gather setup
    } u;
    __shared__ float om[TW][28];                               // 1792 B conv outputs

    const int tid  = threadIdx.x;
    const int lane = tid & 63;
    const int wave = tid >> 6;
    const int pl = lane & 15;
    const int lg = lane >> 4;
    const int off_e = lg * 128 + ((pl ^ lg) << 3);
    const int off_o = lg * 128 + ((pl ^ (lg + 4)) << 3);

    // XCD swizzle: 8192 blocks, %8==0 -> each XCD owns one full image b.
    const int swz = (blockIdx.x & 7) * 1024 + (blockIdx.x >> 3);
    const int bw = swz & 7;
    const int h  = (swz >> 3) & 127;
    const int b  = swz >> 10;
    const int w0 = bw * TW;

    // -------- conv via MFMA, A-fragments straight from global -------------------
    // wave = (nh = N-half, kh = K-half); 9 K-steps x (hi + lo) = 18 MFMA / wave
    const int nh = wave & 1, kh = wave >> 1;
    const unsigned short* Bc = wc + (nh * 16 + pl) * KTOT;
    float4v acc = {0.f, 0.f, 0.f, 0.f};
    const short8v zfrag = {0, 0, 0, 0, 0, 0, 0, 0};
#pragma unroll
    for (int ks9 = 0; ks9 < 9; ++ks9) {
        const int ksg = kh * 9 + ks9;
        const int kap = ksg * 32 + lg * 8;     // lane's first kappa
        const int tap = kap >> 6;
        const int c   = kap & 63;
        const int ky = tap / 3, kx = tap - ky * 3;
        const int y  = h + ky - 1;
        const int xg = w0 + pl + kx - 1;
        const bool valid = ((unsigned)y < (unsigned)HH) && ((unsigned)xg < (unsigned)WW);
        const int off = ((b * HH + y) * WW + xg) * CC + c;
        const short8v bv = *(const short8v*)(Bc + ksg * 32 + lg * 8);
        short8v ah, al;
        if (HASB) {
            ah = valid ? *(const short8v*)(xh + off) : zfrag;
            al = valid ? *(const short8v*)(xl + off) : zfrag;
        } else {
            float4 v0 = make_float4(0.f, 0.f, 0.f, 0.f), v1 = v0;
            if (valid) {
                v0 = *(const float4*)(x + off);
                v1 = *(const float4*)(x + off + 4);
            }
            float vv[8] = {v0.x, v0.y, v0.z, v0.w, v1.x, v1.y, v1.z, v1.w};
            union { short8v v; unsigned short s[8]; } uh, ul;
#pragma unroll
            for (int j = 0; j < 8; ++j) {
                unsigned short h0 = f2bf(vv[j]);
                uh.s[j] = h0;
                ul.s[j] = f2bf(vv[j] - bf2f(h0));
            }
            ah = uh.v; al = ul.v;
        }
        acc = __builtin_amdgcn_mfma_f32_16x16x32_bf16(ah, bv, acc, 0, 0, 0);
        acc = __builtin_amdgcn_mfma_f32_16x16x32_bf16(al, bv, acc, 0, 0, 0);
    }
#pragma unroll
    for (int r = 0; r < 4; ++r)
        u.ps2[wave][lg * 4 + r][pl] = acc[r];
    __syncthreads();

    // -------- reduce partials -> om[pixel][27] ------------------------------------
    for (int idx = tid; idx < TW * 27; idx += 256) {
        int p = idx / 27, o = idx % 27;
        int nhh = o >> 4, ol = o & 15;
        om[p][o] = u.ps2[nhh][p][ol] + u.ps2[2 + nhh][p][ol];
    }
    __syncthreads();

    // -------- gather setup: per (pixel,tap) corner bases + folded weights ---------
    if (tid < 144) {
        int p = tid / 9, k = tid - (tid / 9) * 9;
        float dy = om[p][2 * k], dx = om[p][2 * k + 1];
        float m  = 1.f / (1.f + __expf(-om[p][18 + k]));
        float py = (float)(h + (k / 3) - 1) + dy;
        float px = (float)(w0 + p + (k % 3) - 1) + dx;
        float y0 = floorf(py), x0 = floorf(px);
        float ly = py - y0, lx = px - x0;
        bool vy0 = (y0 >= 0.f)  && (y0 <= 127.f);
        bool vy1 = (y0 >= -1.f) && (y0 <= 126.f);
        bool vx0 = (x0 >= 0.f)  && (x0 <= 127.f);
        bool vx1 = (x0 >= -1.f) && (x0 <= 126.f);
        float wy0 = 1.f - ly, wx0 = 1.f - lx;
        int iy0 = (int)fminf(fmaxf(y0, 0.f), 127.f);
        int iy1 = (int)fminf(fmaxf(y0 + 1.f, 0.f), 127.f);
        int ix0 = (int)fminf(fmaxf(x0, 0.f), 127.f);
        int ix1 = (int)fminf(fmaxf(x0 + 1.f, 0.f), 127.f);
        int base = b * (HH * WW * CC);
        u.gs.c[tid][0] = base + (iy0 * WW + ix0) * CC;
        u.gs.c[tid][1] = base + (iy0 * WW + ix1) * CC;
        u.gs.c[tid][2] = base + (iy1 * WW + ix0) * CC;
        u.gs.c[tid][3] = base + (iy1 * WW + ix1) * CC;
        u.gs.w[tid][0] = (vy0 && vx0) ? wy0 * wx0 * m : 0.f;
        u.gs.w[tid][1] = (vy0 && vx1) ? wy0 * lx  * m : 0.f;
        u.gs.w[tid][2] = (vy1 && vx0) ? ly  * wx0 * m : 0.f;
        u.gs.w[tid][3] = (vy1 && vx1) ? ly  * lx  * m : 0.f;
    }
    __syncthreads();

    // -------- gather: 1152 tasks (pair, c8); 8 lanes coalesce 128B per corner -----
    if (HASB) {
        for (int t = tid; t < 1152; t += 256) {
            int pair = t >> 3, c8 = t & 7;
            int p = pair / 9, k = pair - (pair / 9) * 9;
            int4   cc = *(const int4*)(&u.gs.c[pair][0]);
            float4 wv = *(const float4*)(&u.gs.w[pair][0]);
            int co = c8 * 8;
            uint4 u00 = *(const uint4*)(xh + cc.x + co);
            uint4 u01 = *(const uint4*)(xh + cc.y + co);
            uint4 u10 = *(const uint4*)(xh + cc.z + co);
            uint4 u11 = *(const uint4*)(xh + cc.w + co);
            const unsigned* a00 = (const unsigned*)&u00;
            const unsigned* a01 = (const unsigned*)&u01;
            const unsigned* a10 = (const unsigned*)&u10;
            const unsigned* a11 = (const unsigned*)&u11;
            unsigned qq[4];
#pragma unroll
            for (int jj = 0; jj < 4; ++jj) {
                float rl = wv.x * bf2f_lo(a00[jj]) + wv.y * bf2f_lo(a01[jj])
                         + wv.z * bf2f_lo(a10[jj]) + wv.w * bf2f_lo(a11[jj]);
                float rh = wv.x * bf2f_hi(a00[jj]) + wv.y * bf2f_hi(a01[jj])
                         + wv.z * bf2f_hi(a10[jj]) + wv.w * bf2f_hi(a11[jj]);
                qq[jj] = (unsigned)f2bf(rl) | ((unsigned)f2bf(rh) << 16);
            }
            *(uint4*)(ims + frag_addr(p, k * 64 + co)) = make_uint4(qq[0], qq[1], qq[2], qq[3]);
        }
    } else {
        for (int t = tid; t < 1152; t += 256) {
            int pair = t >> 3, c8 = t & 7;
            int p = pair / 9, k = pair - (pair / 9) * 9;
            int4   cc = *(const int4*)(&u.gs.c[pair][0]);
            float4 wv = *(const float4*)(&u.gs.w[pair][0]);
            int co = c8 * 8;
            float r[8];
#pragma unroll
            for (int half = 0; half < 2; ++half) {
                float4 v00 = *(const float4*)(x + cc.x + co + half * 4);
                float4 v01 = *(const float4*)(x + cc.y + co + half * 4);
                float4 v10 = *(const float4*)(x + cc.z + co + half * 4);
                float4 v11 = *(const float4*)(x + cc.w + co + half * 4);
                r[half * 4 + 0] = wv.x * v00.x + wv.y * v01.x + wv.z * v10.x + wv.w * v11.x;
                r[half * 4 + 1] = wv.x * v00.y + wv.y * v01.y + wv.z * v10.y + wv.w * v11.y;
                r[half * 4 + 2] = wv.x * v00.z + wv.y * v01.z + wv.z * v10.z + wv.w * v11.z;
                r[half * 4 + 3] = wv.x * v00.w + wv.y * v01.w + wv.z * v10.w + wv.w * v11.w;
            }
            unsigned qq[4];
#pragma unroll
            for (int jj = 0; jj < 4; ++jj)
                qq[jj] = (unsigned)f2bf(r[2 * jj]) | ((unsigned)f2bf(r[2 * jj + 1]) << 16);
            *(uint4*)(ims + frag_addr(p, k * 64 + co)) = make_uint4(qq[0], qq[1], qq[2], qq[3]);
        }
    }
    __syncthreads();

    // -------- main einsum: wave owns 16 outputs ------------------------------------
    {
        const unsigned short* Bp = fb + (wave * 16 + pl) * KTOT;
        float4v acc2 = {0.f, 0.f, 0.f, 0.f};
#pragma unroll
        for (int ks = 0; ks < 18; ++ks) {
            short8v a  = *(const short8v*)(ims + ks * 512 + ((ks & 1) ? off_o : off_e));
            short8v bv = *(const short8v*)(Bp + ks * 32 + lg * 8);
            acc2 = __builtin_amdgcn_mfma_f32_16x16x32_bf16(a, bv, acc2, 0, 0, 0);
        }
        const int o = wave * 16 + pl;
        const size_t rowbase = (size_t)(b * HH + h) * WW + w0;
#pragma unroll
        for (int r = 0; r < 4; ++r) {
            int p = lg * 4 + r;
            out[(rowbase + p) * OUTC + o] = acc2[r];
        }
    }
}

extern "C" void kernel_launch(void* const* d_in, const int* in_sizes, int n_in,
                              void* d_out, int out_size, void* d_ws, size_t ws_size,
                              hipStream_t stream) {
    const float* x    = (const float*)d_in[0];
    const float* offk = (const float*)d_in[1];
    const float* mk   = (const float*)d_in[2];
    const float* filt = (const float*)d_in[3];
    float* out = (float*)d_out;
    unsigned short* fb = (unsigned short*)d_ws;                 // 73728 B
    unsigned short* wc = fb + OUTC * KTOT;                      // 36864 B
    unsigned short* xh = wc + 32 * KTOT;                        // 16.78 MB
    unsigned short* xl = xh + NELEM;                            // 16.78 MB
    size_t need = (size_t)(OUTC + 32) * KTOT * 2 + (size_t)NELEM * 4;
    int do_x = (ws_size >= need) ? 1 : 0;
    prep_all<<<144 + (do_x ? 4096 : 0), 256, 0, stream>>>(x, offk, mk, filt, fb, wc, xh, xl, do_x);
    if (do_x)
        deform_conv_fused<1><<<BB * HH * (WW / TW), 256, 0, stream>>>(x, xh, xl, fb, wc, out);
    else
        deform_conv_fused<0><<<BB * HH * (WW / TW), 256, 0, stream>>>(x, xh, xl, fb, wc, out);
}